// Round 2
// baseline (24243.721 us; speedup 1.0000x reference)
//
#include <hip/hip_runtime.h>

#define N_USERS 100000
#define N_ITEMS 50000
#define NTOT    150000        // N_USERS + N_ITEMS
#define E       128
#define NNZ     4800000
#define BATCH   4096
#define NL      3
#define ROWS_PER_BLOCK 32

// ---------------------------------------------------------------------------
// Copy user_emb / item_emb into the working "ego" buffer A (float4 vectorized)
__global__ __launch_bounds__(256) void init_ego(const float* __restrict__ ue,
                                                const float* __restrict__ ie,
                                                float* __restrict__ A) {
    long long i = (long long)blockIdx.x * blockDim.x + threadIdx.x;  // float4 idx
    const long long nU   = (long long)N_USERS * E / 4;
    const long long nTot = (long long)NTOT * E / 4;
    if (i < nU)        ((float4*)A)[i] = ((const float4*)ue)[i];
    else if (i < nTot) ((float4*)A)[i] = ((const float4*)ie)[i - nU];
}

// ---------------------------------------------------------------------------
// CSR build step 1: histogram of row indices.
__global__ __launch_bounds__(256) void hist_kernel(const int* __restrict__ row,
                                                   int* __restrict__ hist) {
    int i = blockIdx.x * blockDim.x + threadIdx.x;
    const int stride = gridDim.x * blockDim.x;
    for (; i < NNZ; i += stride) atomicAdd(&hist[row[i]], 1);
}

// CSR build step 2: exclusive scan hist[0..NTOT) -> rowptr[0..NTOT].
// Single block, 1024 threads, chunked Hillis-Steele.
__global__ __launch_bounds__(1024) void scan_kernel(const int* __restrict__ hist,
                                                    int* __restrict__ rowptr) {
    __shared__ int buf[1024];
    __shared__ int carry_s;
    if (threadIdx.x == 0) carry_s = 0;
    __syncthreads();
    for (int base = 0; base < NTOT; base += 1024) {
        const int idx = base + threadIdx.x;
        const int x = (idx < NTOT) ? hist[idx] : 0;
        buf[threadIdx.x] = x;
        __syncthreads();
        for (int off = 1; off < 1024; off <<= 1) {
            const int v = (threadIdx.x >= off) ? buf[threadIdx.x - off] : 0;
            __syncthreads();
            buf[threadIdx.x] += v;
            __syncthreads();
        }
        if (idx < NTOT) rowptr[idx] = carry_s + buf[threadIdx.x] - x;  // exclusive
        __syncthreads();
        if (threadIdx.x == 0) carry_s += buf[1023];
        __syncthreads();
    }
    if (threadIdx.x == 0) rowptr[NTOT] = carry_s;
}

// CSR build step 3: cursor = rowptr copy.
__global__ __launch_bounds__(256) void copy_int(const int* __restrict__ src,
                                                int* __restrict__ dst, int n) {
    const int i = blockIdx.x * blockDim.x + threadIdx.x;
    if (i < n) dst[i] = src[i];
}

// CSR build step 4: scatter edges into CSR order.
__global__ __launch_bounds__(256) void scatter_kernel(const int* __restrict__ row,
                                                      const int* __restrict__ col,
                                                      const float* __restrict__ val,
                                                      int* __restrict__ cursor,
                                                      int* __restrict__ ccol,
                                                      float* __restrict__ cval) {
    int i = blockIdx.x * blockDim.x + threadIdx.x;
    const int stride = gridDim.x * blockDim.x;
    for (; i < NNZ; i += stride) {
        const int r = row[i];
        const int p = atomicAdd(&cursor[r], 1);
        ccol[p] = col[i];
        cval[p] = val[i];
    }
}

// ---------------------------------------------------------------------------
// CSR SpMM: one wave per row, each lane owns 2 consecutive floats of the
// 128-wide row. Register accumulation, single streaming store — no atomics.
__global__ __launch_bounds__(256) void spmm_csr(const int* __restrict__ rowptr,
                                                const int* __restrict__ cols,
                                                const float* __restrict__ vals,
                                                const float* __restrict__ x,
                                                float* __restrict__ out) {
    const int wave = (blockIdx.x * blockDim.x + threadIdx.x) >> 6;
    const int lane = threadIdx.x & 63;
    const int nw   = gridDim.x * (blockDim.x >> 6);
    for (int r = wave; r < NTOT; r += nw) {
        const int s = rowptr[r];
        const int e = rowptr[r + 1];
        float2 a0 = {0.f, 0.f}, a1 = {0.f, 0.f};
        int i = s;
        for (; i + 1 < e; i += 2) {          // 2-deep for two outstanding gathers
            const int   c0 = cols[i],     c1 = cols[i + 1];
            const float v0 = vals[i],     v1 = vals[i + 1];
            const float2 x0 = ((const float2*)(x + (size_t)c0 * E))[lane];
            const float2 x1 = ((const float2*)(x + (size_t)c1 * E))[lane];
            a0.x = fmaf(v0, x0.x, a0.x);  a0.y = fmaf(v0, x0.y, a0.y);
            a1.x = fmaf(v1, x1.x, a1.x);  a1.y = fmaf(v1, x1.y, a1.y);
        }
        if (i < e) {
            const int   c0 = cols[i];
            const float v0 = vals[i];
            const float2 x0 = ((const float2*)(x + (size_t)c0 * E))[lane];
            a0.x = fmaf(v0, x0.x, a0.x);  a0.y = fmaf(v0, x0.y, a0.y);
        }
        float2 acc = {a0.x + a1.x, a0.y + a1.y};
        ((float2*)(out + (size_t)r * E))[lane] = acc;
    }
}

// ---------------------------------------------------------------------------
// Fallback SpMM (atomic scatter) if workspace is too small for CSR.
__global__ __launch_bounds__(256) void spmm_atomic(const int* __restrict__ row,
                                                   const int* __restrict__ col,
                                                   const float* __restrict__ val,
                                                   const float* __restrict__ x,
                                                   float* __restrict__ out) {
    const int wave   = (blockIdx.x * blockDim.x + threadIdx.x) >> 6;
    const int lane   = threadIdx.x & 63;
    const int nwaves = gridDim.x * (blockDim.x >> 6);
    for (int e = wave; e < NNZ; e += nwaves) {
        const int   r = row[e];
        const int   c = col[e];
        const float v = val[e];
        const float2 xv = ((const float2*)(x + (size_t)c * E))[lane];
        float* o = out + (size_t)r * E + lane * 2;
        unsafeAtomicAdd(o,     v * xv.x);
        unsafeAtomicAdd(o + 1, v * xv.y);
    }
}

// ---------------------------------------------------------------------------
// ego = concat(Bp, Cd) @ W[k] + bias[k]
__global__ __launch_bounds__(128) void linear_kernel(const float* __restrict__ Bp,
                                                     const float* __restrict__ Cd,
                                                     const float* __restrict__ Wk,
                                                     const float* __restrict__ bk,
                                                     float* __restrict__ out) {
    __shared__ float sB[ROWS_PER_BLOCK][E];
    __shared__ float sC[ROWS_PER_BLOCK][E];
    const int j  = threadIdx.x;              // output column 0..127
    const int r0 = blockIdx.x * ROWS_PER_BLOCK;

    #pragma unroll
    for (int r = 0; r < ROWS_PER_BLOCK; ++r) {
        int rr = r0 + r; if (rr >= NTOT) rr = NTOT - 1;
        sB[r][j] = Bp[(size_t)rr * E + j];
        sC[r][j] = Cd[(size_t)rr * E + j];
    }
    __syncthreads();

    float acc[ROWS_PER_BLOCK];
    const float bj = bk[j];
    #pragma unroll
    for (int r = 0; r < ROWS_PER_BLOCK; ++r) acc[r] = bj;

    #pragma unroll 4
    for (int i = 0; i < E; ++i) {
        const float w = Wk[(size_t)i * E + j];
        #pragma unroll
        for (int r = 0; r < ROWS_PER_BLOCK; ++r) acc[r] = fmaf(sB[r][i], w, acc[r]);
    }
    #pragma unroll 4
    for (int i = 0; i < E; ++i) {
        const float w = Wk[(size_t)(E + i) * E + j];
        #pragma unroll
        for (int r = 0; r < ROWS_PER_BLOCK; ++r) acc[r] = fmaf(sC[r][i], w, acc[r]);
    }

    #pragma unroll
    for (int r = 0; r < ROWS_PER_BLOCK; ++r) {
        const int rr = r0 + r;
        if (rr < NTOT) out[(size_t)rr * E + j] = acc[r];
    }
}

// ---------------------------------------------------------------------------
__global__ __launch_bounds__(256) void gather_out(const float* __restrict__ A,
                                                  const int* __restrict__ users,
                                                  const int* __restrict__ items,
                                                  float* __restrict__ out) {
    const int t = blockIdx.x * blockDim.x + threadIdx.x;
    if (t >= 2 * BATCH * E) return;
    const int j = t & (E - 1);
    const int b = t >> 7;
    if (b < BATCH) {
        out[t] = A[(size_t)users[b] * E + j];
    } else {
        const int bb = b - BATCH;
        out[t] = A[(size_t)(N_USERS + items[bb]) * E + j];
    }
}

// ---------------------------------------------------------------------------
extern "C" void kernel_launch(void* const* d_in, const int* in_sizes, int n_in,
                              void* d_out, int out_size, void* d_ws, size_t ws_size,
                              hipStream_t stream) {
    const float* user_emb = (const float*)d_in[0];
    const float* item_emb = (const float*)d_in[1];
    const float* adj_val  = (const float*)d_in[2];
    const float* hp_val   = (const float*)d_in[3];
    const float* W        = (const float*)d_in[4];
    const float* bias     = (const float*)d_in[5];
    const int*   adj_row  = (const int*)d_in[6];
    const int*   adj_col  = (const int*)d_in[7];
    const int*   hp_row   = (const int*)d_in[8];
    const int*   hp_col   = (const int*)d_in[9];
    const int*   users    = (const int*)d_in[10];
    const int*   items    = (const int*)d_in[11];
    float* out = (float*)d_out;

    // ---- workspace layout ----
    float* A  = (float*)d_ws;
    float* Bp = A  + (size_t)NTOT * E;
    float* Cd = Bp + (size_t)NTOT * E;
    int*   rowptrA = (int*)(Cd + (size_t)NTOT * E);
    int*   rowptrH = rowptrA + (NTOT + 1);
    int*   cursorA = rowptrH + (NTOT + 1);
    int*   cursorH = cursorA + NTOT;
    int*   colA    = cursorH + NTOT;
    int*   colH    = colA + NNZ;
    float* valA    = (float*)(colH + NNZ);
    float* valH    = valA + NNZ;
    const size_t needed = (size_t)(valH + NNZ - (float*)d_ws) * sizeof(float);

    // init ego = concat(user_emb, item_emb)
    {
        const long long n4 = (long long)NTOT * E / 4;
        init_ego<<<(int)((n4 + 255) / 256), 256, 0, stream>>>(user_emb, item_emb, A);
    }

    const bool use_csr = (ws_size >= needed);

    if (use_csr) {
        // ---- build CSR for both adjacencies (once; reused across 3 layers) ----
        hipMemsetAsync(cursorA, 0, (size_t)2 * NTOT * sizeof(int), stream);  // cursorA+cursorH
        hist_kernel<<<2048, 256, 0, stream>>>(adj_row, cursorA);
        hist_kernel<<<2048, 256, 0, stream>>>(hp_row,  cursorH);
        scan_kernel<<<1, 1024, 0, stream>>>(cursorA, rowptrA);
        scan_kernel<<<1, 1024, 0, stream>>>(cursorH, rowptrH);
        copy_int<<<(NTOT + 255) / 256, 256, 0, stream>>>(rowptrA, cursorA, NTOT);
        copy_int<<<(NTOT + 255) / 256, 256, 0, stream>>>(rowptrH, cursorH, NTOT);
        scatter_kernel<<<2048, 256, 0, stream>>>(adj_row, adj_col, adj_val, cursorA, colA, valA);
        scatter_kernel<<<2048, 256, 0, stream>>>(hp_row,  hp_col,  hp_val,  cursorH, colH, valH);

        for (int k = 0; k < NL; ++k) {
            spmm_csr<<<2048, 256, 0, stream>>>(rowptrA, colA, valA, A, Bp);
            spmm_csr<<<2048, 256, 0, stream>>>(rowptrH, colH, valH, A, Cd);
            linear_kernel<<<(NTOT + ROWS_PER_BLOCK - 1) / ROWS_PER_BLOCK, 128, 0, stream>>>(
                Bp, Cd, W + (size_t)k * 2 * E * E, bias + (size_t)k * E, A);
        }
    } else {
        // ---- fallback: atomic scatter SpMM ----
        for (int k = 0; k < NL; ++k) {
            hipMemsetAsync(Bp, 0, (size_t)2 * NTOT * E * sizeof(float), stream);
            spmm_atomic<<<2048, 256, 0, stream>>>(adj_row, adj_col, adj_val, A, Bp);
            spmm_atomic<<<2048, 256, 0, stream>>>(hp_row,  hp_col,  hp_val,  A, Cd);
            linear_kernel<<<(NTOT + ROWS_PER_BLOCK - 1) / ROWS_PER_BLOCK, 128, 0, stream>>>(
                Bp, Cd, W + (size_t)k * 2 * E * E, bias + (size_t)k * E, A);
        }
    }

    gather_out<<<(2 * BATCH * E + 255) / 256, 256, 0, stream>>>(A, users, items, out);
}

// Round 3
// 3252.595 us; speedup vs baseline: 7.4537x; 7.4537x over previous
//
#include <hip/hip_runtime.h>

#define N_USERS 100000
#define N_ITEMS 50000
#define NTOT    150000        // N_USERS + N_ITEMS
#define E       128
#define NNZ     4800000
#define BATCH   4096
#define TILE    16            // rows per block in fused kernels (150000 = 16*9375 exact)

// ---------------------------------------------------------------------------
// ego = concat(user_emb, item_emb), float4 vectorized
__global__ __launch_bounds__(256) void init_ego(const float* __restrict__ ue,
                                                const float* __restrict__ ie,
                                                float* __restrict__ A) {
    long long i = (long long)blockIdx.x * blockDim.x + threadIdx.x;
    const long long nU   = (long long)N_USERS * E / 4;
    const long long nTot = (long long)NTOT * E / 4;
    if (i < nU)        ((float4*)A)[i] = ((const float4*)ue)[i];
    else if (i < nTot) ((float4*)A)[i] = ((const float4*)ie)[i - nU];
}

// ---------------------------------------------------------------------------
// CSR build step 1: histogram of row indices (hist pre-zeroed by memset).
__global__ __launch_bounds__(256) void hist_kernel(const int* __restrict__ row,
                                                   int* __restrict__ hist) {
    int i = blockIdx.x * blockDim.x + threadIdx.x;
    const int stride = gridDim.x * blockDim.x;
    for (; i < NNZ; i += stride) atomicAdd(&hist[row[i]], 1);
}

// CSR build step 2: exclusive scan hist[0..NTOT) -> rowptr[0..NTOT].
// One block, 1024 threads, 4 elements/thread per chunk (37 chunks).
__global__ __launch_bounds__(1024) void scan_kernel(const int* __restrict__ hist,
                                                    int* __restrict__ rowptr) {
    __shared__ int buf[1024];
    __shared__ int carry_s;
    const int t = threadIdx.x;
    if (t == 0) carry_s = 0;
    __syncthreads();
    for (int base = 0; base < NTOT; base += 4096) {
        const int i0 = base + t * 4;
        const int a0 = (i0 + 0 < NTOT) ? hist[i0 + 0] : 0;
        const int a1 = (i0 + 1 < NTOT) ? hist[i0 + 1] : 0;
        const int a2 = (i0 + 2 < NTOT) ? hist[i0 + 2] : 0;
        const int a3 = (i0 + 3 < NTOT) ? hist[i0 + 3] : 0;
        const int s = a0 + a1 + a2 + a3;
        buf[t] = s;
        __syncthreads();
        for (int off = 1; off < 1024; off <<= 1) {
            const int v = (t >= off) ? buf[t - off] : 0;
            __syncthreads();
            buf[t] += v;
            __syncthreads();
        }
        const int excl = carry_s + buf[t] - s;
        if (i0 + 0 < NTOT) rowptr[i0 + 0] = excl;
        if (i0 + 1 < NTOT) rowptr[i0 + 1] = excl + a0;
        if (i0 + 2 < NTOT) rowptr[i0 + 2] = excl + a0 + a1;
        if (i0 + 3 < NTOT) rowptr[i0 + 3] = excl + a0 + a1 + a2;
        __syncthreads();
        if (t == 0) carry_s += buf[1023];
        __syncthreads();
    }
    if (t == 0) rowptr[NTOT] = carry_s;
}

// CSR build step 3: cursor = copy of rowptr starts.
__global__ __launch_bounds__(256) void copy_int(const int* __restrict__ src,
                                                int* __restrict__ dst, int n) {
    const int i = blockIdx.x * blockDim.x + threadIdx.x;
    if (i < n) dst[i] = src[i];
}

// CSR build step 4: scatter edges into CSR order.
// PERM: store original edge index. else: store reordered col+val directly.
template<bool PERM>
__global__ __launch_bounds__(256) void scatter_kernel(const int* __restrict__ row,
                                                      const int* __restrict__ col,
                                                      const float* __restrict__ val,
                                                      int* __restrict__ cursor,
                                                      int* __restrict__ idx_or_col,
                                                      float* __restrict__ valR) {
    int i = blockIdx.x * blockDim.x + threadIdx.x;
    const int stride = gridDim.x * blockDim.x;
    for (; i < NNZ; i += stride) {
        const int r = row[i];
        const int p = atomicAdd(&cursor[r], 1);
        if constexpr (PERM) {
            idx_or_col[p] = i;
        } else {
            idx_or_col[p] = col[i];
            valR[p]       = val[i];
        }
    }
}

// ---------------------------------------------------------------------------
// Accumulate one CSR row (128-wide, float2 per lane) in registers.
template<bool PERM>
__device__ __forceinline__ float2 row_accum(const int* __restrict__ rp,
                                            const int* __restrict__ idx,   // perm or colR
                                            const float* __restrict__ valR,
                                            const int* __restrict__ col0,
                                            const float* __restrict__ val0,
                                            const float* __restrict__ x, int r, int lane) {
    const int s = rp[r];
    const int e = rp[r + 1];
    float2 a0 = {0.f, 0.f}, a1 = {0.f, 0.f};
    int i = s;
    for (; i + 1 < e; i += 2) {
        int c0, c1; float v0, v1;
        if constexpr (PERM) {
            const int p0 = idx[i], p1 = idx[i + 1];
            c0 = col0[p0]; c1 = col0[p1];
            v0 = val0[p0]; v1 = val0[p1];
        } else {
            c0 = idx[i];  c1 = idx[i + 1];
            v0 = valR[i]; v1 = valR[i + 1];
        }
        const float2 x0 = ((const float2*)(x + (size_t)c0 * E))[lane];
        const float2 x1 = ((const float2*)(x + (size_t)c1 * E))[lane];
        a0.x = fmaf(v0, x0.x, a0.x);  a0.y = fmaf(v0, x0.y, a0.y);
        a1.x = fmaf(v1, x1.x, a1.x);  a1.y = fmaf(v1, x1.y, a1.y);
    }
    if (i < e) {
        int c0; float v0;
        if constexpr (PERM) { const int p0 = idx[i]; c0 = col0[p0]; v0 = val0[p0]; }
        else                {             c0 = idx[i]; v0 = valR[i]; }
        const float2 x0 = ((const float2*)(x + (size_t)c0 * E))[lane];
        a0.x = fmaf(v0, x0.x, a0.x);  a0.y = fmaf(v0, x0.y, a0.y);
    }
    return make_float2(a0.x + a1.x, a0.y + a1.y);
}

// ---------------------------------------------------------------------------
// Fused layer: per block, compute TILE rows of pos (adj) and dis (hp) into LDS,
// then ego_next = concat(pos,dis) @ W + b  written straight out. No Bp/Cd.
// FINAL: rows come from users/items and outputs go to d_out slot-major.
template<bool PERM, bool FINAL>
__global__ __launch_bounds__(256) void fused_layer(
    const float* __restrict__ A,
    const int* __restrict__ rpA, const int* __restrict__ idxA, const float* __restrict__ valRA,
    const int* __restrict__ rpH, const int* __restrict__ idxH, const float* __restrict__ valRH,
    const int* __restrict__ colA0, const float* __restrict__ valA0,
    const int* __restrict__ colH0, const float* __restrict__ valH0,
    const float* __restrict__ Wk, const float* __restrict__ bk,
    const int* __restrict__ users, const int* __restrict__ items,
    float* __restrict__ out) {
    __shared__ float sP[TILE][E];
    __shared__ float sD[TILE][E];
    const int t    = threadIdx.x;
    const int lane = t & 63;
    const int wv   = t >> 6;                 // wave 0..3, 4 rows each
    const int r0   = blockIdx.x * TILE;

    // ---- phase 1: CSR register accumulation, rows -> LDS ----
    for (int rl = wv * 4; rl < wv * 4 + 4; ++rl) {
        const int slot = r0 + rl;
        int r = slot;
        if constexpr (FINAL)
            r = (slot < BATCH) ? users[slot] : (N_USERS + items[slot - BATCH]);
        const float2 p = row_accum<PERM>(rpA, idxA, valRA, colA0, valA0, A, r, lane);
        ((float2*)&sP[rl][0])[lane] = p;
        const float2 d = row_accum<PERM>(rpH, idxH, valRH, colH0, valH0, A, r, lane);
        ((float2*)&sD[rl][0])[lane] = d;
    }
    __syncthreads();

    // ---- phase 2: [TILE,256] @ [256,128] + bias ----
    const int j = t & (E - 1);               // output column
    const int h = t >> 7;                    // row half: 0 or 1 (8 rows each)
    float acc[8];
    const float bj = bk[j];
    #pragma unroll
    for (int rr = 0; rr < 8; ++rr) acc[rr] = bj;

    #pragma unroll 4
    for (int i = 0; i < E; ++i) {
        const float w = Wk[(size_t)i * E + j];          // top half of W (pos)
        #pragma unroll
        for (int rr = 0; rr < 8; ++rr) acc[rr] = fmaf(sP[h * 8 + rr][i], w, acc[rr]);
    }
    #pragma unroll 4
    for (int i = 0; i < E; ++i) {
        const float w = Wk[(size_t)(E + i) * E + j];    // bottom half of W (dis)
        #pragma unroll
        for (int rr = 0; rr < 8; ++rr) acc[rr] = fmaf(sD[h * 8 + rr][i], w, acc[rr]);
    }

    #pragma unroll
    for (int rr = 0; rr < 8; ++rr)
        out[(size_t)(r0 + h * 8 + rr) * E + j] = acc[rr];
}

// ---------------------------------------------------------------------------
extern "C" void kernel_launch(void* const* d_in, const int* in_sizes, int n_in,
                              void* d_out, int out_size, void* d_ws, size_t ws_size,
                              hipStream_t stream) {
    const float* user_emb = (const float*)d_in[0];
    const float* item_emb = (const float*)d_in[1];
    const float* adj_val  = (const float*)d_in[2];
    const float* hp_val   = (const float*)d_in[3];
    const float* W        = (const float*)d_in[4];
    const float* bias     = (const float*)d_in[5];
    const int*   adj_row  = (const int*)d_in[6];
    const int*   adj_col  = (const int*)d_in[7];
    const int*   hp_row   = (const int*)d_in[8];
    const int*   hp_col   = (const int*)d_in[9];
    const int*   users    = (const int*)d_in[10];
    const int*   items    = (const int*)d_in[11];
    float* out = (float*)d_out;

    // ---- workspace layout ----
    float* buf0 = (float*)d_ws;                       // ego ping
    float* buf1 = buf0 + (size_t)NTOT * E;            // ego pong
    int*   rpA  = (int*)(buf1 + (size_t)NTOT * E);
    int*   rpH  = rpA + (NTOT + 1);
    int*   csrA = rpH + (NTOT + 1);                   // perm  (NNZ)  or colR (NNZ)
    int*   csrH = csrA + NNZ;
    float* valRA = (float*)(csrH + NNZ);              // reordered vals (REORDER tier only)
    float* valRH = valRA + NNZ;

    const size_t need_reorder = (size_t)(valRH + NNZ - (float*)d_ws) * sizeof(float); // 231.6 MB
    const bool reorder = (ws_size >= need_reorder);

    // cursors are temp: alias into buf1 (only written by fused layer 0, later)
    int* curA = (int*)buf1;
    int* curH = curA + NTOT;

    // ---- init ego ----
    {
        const long long n4 = (long long)NTOT * E / 4;
        init_ego<<<(int)((n4 + 255) / 256), 256, 0, stream>>>(user_emb, item_emb, buf0);
    }

    // ---- build CSR (both adjacencies, once; reused across all 3 layers) ----
    hipMemsetAsync(curA, 0, (size_t)2 * NTOT * sizeof(int), stream);
    hist_kernel<<<2048, 256, 0, stream>>>(adj_row, curA);
    hist_kernel<<<2048, 256, 0, stream>>>(hp_row,  curH);
    scan_kernel<<<1, 1024, 0, stream>>>(curA, rpA);
    scan_kernel<<<1, 1024, 0, stream>>>(curH, rpH);
    copy_int<<<(NTOT + 255) / 256, 256, 0, stream>>>(rpA, curA, NTOT);
    copy_int<<<(NTOT + 255) / 256, 256, 0, stream>>>(rpH, curH, NTOT);
    if (reorder) {
        scatter_kernel<false><<<2048, 256, 0, stream>>>(adj_row, adj_col, adj_val, curA, csrA, valRA);
        scatter_kernel<false><<<2048, 256, 0, stream>>>(hp_row,  hp_col,  hp_val,  curH, csrH, valRH);
    } else {
        scatter_kernel<true><<<2048, 256, 0, stream>>>(adj_row, adj_col, adj_val, curA, csrA, nullptr);
        scatter_kernel<true><<<2048, 256, 0, stream>>>(hp_row,  hp_col,  hp_val,  curH, csrH, nullptr);
    }

    // ---- 3 layers: k=0 buf0->buf1, k=1 buf1->buf0, k=2 buf0->out (8192 rows only) ----
    const int gridF = NTOT / TILE;            // 9375
    const int gridL = (2 * BATCH) / TILE;     // 512
    #define FUSED_ARGS(IN, OUTP, K, U, I) \
        (IN, rpA, csrA, valRA, rpH, csrH, valRH, adj_col, adj_val, hp_col, hp_val, \
         W + (size_t)(K) * 2 * E * E, bias + (size_t)(K) * E, U, I, OUTP)
    if (reorder) {
        fused_layer<false, false><<<gridF, 256, 0, stream>>>FUSED_ARGS(buf0, buf1, 0, nullptr, nullptr);
        fused_layer<false, false><<<gridF, 256, 0, stream>>>FUSED_ARGS(buf1, buf0, 1, nullptr, nullptr);
        fused_layer<false, true ><<<gridL, 256, 0, stream>>>FUSED_ARGS(buf0, out,  2, users, items);
    } else {
        fused_layer<true, false><<<gridF, 256, 0, stream>>>FUSED_ARGS(buf0, buf1, 0, nullptr, nullptr);
        fused_layer<true, false><<<gridF, 256, 0, stream>>>FUSED_ARGS(buf1, buf0, 1, nullptr, nullptr);
        fused_layer<true, true ><<<gridL, 256, 0, stream>>>FUSED_ARGS(buf0, out,  2, users, items);
    }
    #undef FUSED_ARGS
}

// Round 4
// 2513.176 us; speedup vs baseline: 9.6466x; 1.2942x over previous
//
#include <hip/hip_runtime.h>

#define N_USERS 100000
#define N_ITEMS 50000
#define NTOT    150000        // N_USERS + N_ITEMS
#define E       128
#define NNZ     4800000
#define BATCH   4096
#define TILE    16            // rows per block (150000 = 16*9375, 8192 = 16*512)

// ---------------------------------------------------------------------------
// CSR build 1: histogram of row indices (hist pre-zeroed by memset).
__global__ __launch_bounds__(256) void hist_kernel(const int* __restrict__ row,
                                                   int* __restrict__ hist) {
    int i = blockIdx.x * blockDim.x + threadIdx.x;
    const int stride = gridDim.x * blockDim.x;
    for (; i < NNZ; i += stride) atomicAdd(&hist[row[i]], 1);
}

// CSR build 2: exclusive scan, both adjacencies concurrently (block 0: A, 1: H).
// 1024 threads, 4 elems/thread/chunk, wave-shuffle scan + cross-wave LDS.
__global__ __launch_bounds__(1024) void scan_both(const int* __restrict__ hA,
                                                  const int* __restrict__ hH,
                                                  int* __restrict__ rA,
                                                  int* __restrict__ rH) {
    const int* h = blockIdx.x ? hH : hA;
    int*       r = blockIdx.x ? rH : rA;
    __shared__ int wsum[16];
    __shared__ int woff[17];
    __shared__ int carry;
    const int t = threadIdx.x, lane = t & 63, wv = t >> 6;
    if (t == 0) carry = 0;
    __syncthreads();
    for (int base = 0; base < NTOT; base += 4096) {
        const int i0 = base + t * 4;
        const int a0 = (i0 + 0 < NTOT) ? h[i0 + 0] : 0;
        const int a1 = (i0 + 1 < NTOT) ? h[i0 + 1] : 0;
        const int a2 = (i0 + 2 < NTOT) ? h[i0 + 2] : 0;
        const int a3 = (i0 + 3 < NTOT) ? h[i0 + 3] : 0;
        const int s = a0 + a1 + a2 + a3;
        int x = s;
        #pragma unroll
        for (int off = 1; off < 64; off <<= 1) {
            const int n = __shfl_up(x, off);
            if (lane >= off) x += n;
        }
        if (lane == 63) wsum[wv] = x;
        __syncthreads();
        if (t == 0) {
            int acc = 0;
            #pragma unroll
            for (int w = 0; w < 16; ++w) { woff[w] = acc; acc += wsum[w]; }
            woff[16] = acc;
        }
        __syncthreads();
        const int excl = carry + woff[wv] + (x - s);
        if (i0 + 0 < NTOT) r[i0 + 0] = excl;
        if (i0 + 1 < NTOT) r[i0 + 1] = excl + a0;
        if (i0 + 2 < NTOT) r[i0 + 2] = excl + a0 + a1;
        if (i0 + 3 < NTOT) r[i0 + 3] = excl + a0 + a1 + a2;
        __syncthreads();
        if (t == 0) carry += woff[16];
        __syncthreads();
    }
    if (t == 0) r[NTOT] = carry;
}

// CSR build 3: generic int copy.
__global__ __launch_bounds__(256) void copy_int(const int* __restrict__ src,
                                                int* __restrict__ dst, int n) {
    const int i = blockIdx.x * blockDim.x + threadIdx.x;
    if (i < n) dst[i] = src[i];
}

// CSR build 4: scatter edges into CSR order as interleaved (col, val) int2.
__global__ __launch_bounds__(256) void scatter_kernel(const int* __restrict__ row,
                                                      const int* __restrict__ col,
                                                      const float* __restrict__ val,
                                                      int* __restrict__ cursor,
                                                      int2* __restrict__ ed) {
    int i = blockIdx.x * blockDim.x + threadIdx.x;
    const int stride = gridDim.x * blockDim.x;
    for (; i < NNZ; i += stride) {
        const int r = row[i];
        const int p = atomicAdd(&cursor[r], 1);
        ed[p] = make_int2(col[i], __float_as_int(val[i]));
    }
}

// ---------------------------------------------------------------------------
// Gather-source resolution: layer 0 reads straight from the input embeddings.
template<bool FIRST>
__device__ __forceinline__ const float* srcptr(int c, const float* __restrict__ ue,
                                               const float* __restrict__ ie,
                                               const float* __restrict__ A) {
    if constexpr (FIRST)
        return (c < N_USERS) ? (ue + (size_t)c * E) : (ie + (size_t)(c - N_USERS) * E);
    else
        return A + (size_t)c * E;
}

// Accumulate one CSR row (128-wide, float2/lane), 4 outstanding gathers.
template<bool FIRST>
__device__ __forceinline__ float2 row_accum(const int* __restrict__ rp,
                                            const int2* __restrict__ ed,
                                            const float* __restrict__ ue,
                                            const float* __restrict__ ie,
                                            const float* __restrict__ A,
                                            int r, int lane) {
    const int s = rp[r];
    const int e = rp[r + 1];
    float2 a0{0.f,0.f}, a1{0.f,0.f}, a2{0.f,0.f}, a3{0.f,0.f};
    int i = s;
    for (; i + 3 < e; i += 4) {
        const int2 e0 = ed[i+0], e1 = ed[i+1], e2 = ed[i+2], e3 = ed[i+3];
        const float2 x0 = ((const float2*)srcptr<FIRST>(e0.x, ue, ie, A))[lane];
        const float2 x1 = ((const float2*)srcptr<FIRST>(e1.x, ue, ie, A))[lane];
        const float2 x2 = ((const float2*)srcptr<FIRST>(e2.x, ue, ie, A))[lane];
        const float2 x3 = ((const float2*)srcptr<FIRST>(e3.x, ue, ie, A))[lane];
        const float v0 = __int_as_float(e0.y), v1 = __int_as_float(e1.y);
        const float v2 = __int_as_float(e2.y), v3 = __int_as_float(e3.y);
        a0.x = fmaf(v0, x0.x, a0.x);  a0.y = fmaf(v0, x0.y, a0.y);
        a1.x = fmaf(v1, x1.x, a1.x);  a1.y = fmaf(v1, x1.y, a1.y);
        a2.x = fmaf(v2, x2.x, a2.x);  a2.y = fmaf(v2, x2.y, a2.y);
        a3.x = fmaf(v3, x3.x, a3.x);  a3.y = fmaf(v3, x3.y, a3.y);
    }
    for (; i < e; ++i) {
        const int2 e0 = ed[i];
        const float2 x0 = ((const float2*)srcptr<FIRST>(e0.x, ue, ie, A))[lane];
        const float v0 = __int_as_float(e0.y);
        a0.x = fmaf(v0, x0.x, a0.x);  a0.y = fmaf(v0, x0.y, a0.y);
    }
    return make_float2((a0.x + a1.x) + (a2.x + a3.x),
                       (a0.y + a1.y) + (a2.y + a3.y));
}

// ---------------------------------------------------------------------------
// Fused layer: TILE rows of pos (adj) and dis (hp) into LDS, then
// ego_next = concat(pos,dis) @ W + b written straight out.
// FIRST: gather from ue/ie. FINAL: rows from users/items, out = d_out.
template<bool FIRST, bool FINAL>
__global__ __launch_bounds__(256) void fused_layer(
    const float* __restrict__ A,
    const float* __restrict__ ue, const float* __restrict__ ie,
    const int* __restrict__ rpA, const int2* __restrict__ edA,
    const int* __restrict__ rpH, const int2* __restrict__ edH,
    const float* __restrict__ Wk, const float* __restrict__ bk,
    const int* __restrict__ users, const int* __restrict__ items,
    float* __restrict__ out) {
    __shared__ float sP[TILE][E];
    __shared__ float sD[TILE][E];
    const int t    = threadIdx.x;
    const int lane = t & 63;
    const int wv   = t >> 6;                 // wave 0..3, 4 rows each
    const int r0   = blockIdx.x * TILE;

    // ---- phase 1: CSR register accumulation, rows -> LDS ----
    for (int rl = wv * 4; rl < wv * 4 + 4; ++rl) {
        const int slot = r0 + rl;
        int r = slot;
        if constexpr (FINAL)
            r = (slot < BATCH) ? users[slot] : (N_USERS + items[slot - BATCH]);
        const float2 p = row_accum<FIRST>(rpA, edA, ue, ie, A, r, lane);
        ((float2*)&sP[rl][0])[lane] = p;
        const float2 d = row_accum<FIRST>(rpH, edH, ue, ie, A, r, lane);
        ((float2*)&sD[rl][0])[lane] = d;
    }
    __syncthreads();

    // ---- phase 2: [TILE,256] @ [256,128] + bias ----
    const int j = t & (E - 1);               // output column
    const int h = t >> 7;                    // row half: 0 or 1 (8 rows each)
    float acc[8];
    const float bj = bk[j];
    #pragma unroll
    for (int rr = 0; rr < 8; ++rr) acc[rr] = bj;

    #pragma unroll 4
    for (int i = 0; i < E; ++i) {
        const float w = Wk[(size_t)i * E + j];          // top half (pos)
        #pragma unroll
        for (int rr = 0; rr < 8; ++rr) acc[rr] = fmaf(sP[h * 8 + rr][i], w, acc[rr]);
    }
    #pragma unroll 4
    for (int i = 0; i < E; ++i) {
        const float w = Wk[(size_t)(E + i) * E + j];    // bottom half (dis)
        #pragma unroll
        for (int rr = 0; rr < 8; ++rr) acc[rr] = fmaf(sD[h * 8 + rr][i], w, acc[rr]);
    }

    #pragma unroll
    for (int rr = 0; rr < 8; ++rr)
        out[(size_t)(r0 + h * 8 + rr) * E + j] = acc[rr];
}

// ---------------------------------------------------------------------------
extern "C" void kernel_launch(void* const* d_in, const int* in_sizes, int n_in,
                              void* d_out, int out_size, void* d_ws, size_t ws_size,
                              hipStream_t stream) {
    const float* user_emb = (const float*)d_in[0];
    const float* item_emb = (const float*)d_in[1];
    const float* adj_val  = (const float*)d_in[2];
    const float* hp_val   = (const float*)d_in[3];
    const float* W        = (const float*)d_in[4];
    const float* bias     = (const float*)d_in[5];
    const int*   adj_row  = (const int*)d_in[6];
    const int*   adj_col  = (const int*)d_in[7];
    const int*   hp_row   = (const int*)d_in[8];
    const int*   hp_col   = (const int*)d_in[9];
    const int*   users    = (const int*)d_in[10];
    const int*   items    = (const int*)d_in[11];
    float* out = (float*)d_out;

    // ---- workspace layout: exactly 230,400,000 B (proven available in R1) ----
    float* buf0 = (float*)d_ws;                       // ego ping      76.8 MB
    float* buf1 = buf0 + (size_t)NTOT * E;            // ego pong      76.8 MB
    int2*  edA  = (int2*)(buf1 + (size_t)NTOT * E);   // CSR edges A   38.4 MB
    int2*  edH  = edA + NNZ;                          // CSR edges H   38.4 MB

    // rowptrs live in d_out (4 MB; fully overwritten by the FINAL layer).
    int* rpA = (int*)d_out;
    int* rpH = rpA + (NTOT + 1);
    // cursors alias buf1 (dead until layer 0 writes it).
    int* curA = (int*)buf1;
    int* curH = curA + NTOT;
    // rowptr copies for the FINAL layer live in buf1 (dead during layer 2).
    int* rpA2 = (int*)buf1;
    int* rpH2 = rpA2 + (NTOT + 1);

    // ---- build CSR (once; reused across all 3 layers) ----
    hipMemsetAsync(curA, 0, (size_t)2 * NTOT * sizeof(int), stream);
    hist_kernel<<<2048, 256, 0, stream>>>(adj_row, curA);
    hist_kernel<<<2048, 256, 0, stream>>>(hp_row,  curH);
    scan_both<<<2, 1024, 0, stream>>>(curA, curH, rpA, rpH);
    copy_int<<<(NTOT + 255) / 256, 256, 0, stream>>>(rpA, curA, NTOT);
    copy_int<<<(NTOT + 255) / 256, 256, 0, stream>>>(rpH, curH, NTOT);
    scatter_kernel<<<2048, 256, 0, stream>>>(adj_row, adj_col, adj_val, curA, edA);
    scatter_kernel<<<2048, 256, 0, stream>>>(hp_row,  hp_col,  hp_val,  curH, edH);

    // ---- 3 fused layers ----
    const int gridF = NTOT / TILE;            // 9375
    const int gridL = (2 * BATCH) / TILE;     // 512
    // k=0: (ue,ie) -> buf1
    fused_layer<true, false><<<gridF, 256, 0, stream>>>(
        nullptr, user_emb, item_emb, rpA, edA, rpH, edH,
        W, bias, nullptr, nullptr, buf1);
    // k=1: buf1 -> buf0
    fused_layer<false, false><<<gridF, 256, 0, stream>>>(
        buf1, nullptr, nullptr, rpA, edA, rpH, edH,
        W + (size_t)2 * E * E, bias + E, nullptr, nullptr, buf0);
    // move rowptrs out of d_out before the FINAL layer overwrites it
    copy_int<<<(2 * (NTOT + 1) + 255) / 256, 256, 0, stream>>>(rpA, rpA2, 2 * (NTOT + 1));
    // k=2: buf0 -> d_out (only the 8192 requested rows)
    fused_layer<false, true><<<gridL, 256, 0, stream>>>(
        buf0, nullptr, nullptr, rpA2, edA, rpH2, edH,
        W + (size_t)4 * E * E, bias + 2 * E, users, items, out);
}